// Round 2
// baseline (209.835 us; speedup 1.0000x reference)
//
#include <hip/hip_runtime.h>

// out[t, :] = sum_k scores[t*K+k] * moe[slots[t*K+k], :]
// Specialized: TOPK and vec-per-thread are compile-time; all gather loads are
// issued before any FMA (max memory-level parallelism per wave).
template <int TOPK, int VPT>
__global__ __launch_bounds__(256) void moe_gather_fixed(
    const float* __restrict__ moe,     // [total_slots, hidden]
    const float* __restrict__ scores,  // [total_slots]
    const int*   __restrict__ slots,   // [total_slots]
    float*       __restrict__ out,     // [n_tokens, hidden]
    int hidden) {
    const int t   = blockIdx.x;
    const int tid = threadIdx.x;

    float w[TOPK];
    const float4* rows[TOPK];
#pragma unroll
    for (int k = 0; k < TOPK; ++k) {
        const int s = slots[t * TOPK + k];
        w[k]    = scores[t * TOPK + k];
        rows[k] = (const float4*)(moe + (size_t)s * hidden);
    }

    float4* orow = (float4*)(out + (size_t)t * hidden);

    // Issue ALL loads first (TOPK*VPT outstanding global loads per thread).
    float4 x[VPT][TOPK];
#pragma unroll
    for (int v = 0; v < VPT; ++v)
#pragma unroll
        for (int k = 0; k < TOPK; ++k)
            x[v][k] = rows[k][tid + v * 256];

#pragma unroll
    for (int v = 0; v < VPT; ++v) {
        float4 acc = make_float4(0.f, 0.f, 0.f, 0.f);
#pragma unroll
        for (int k = 0; k < TOPK; ++k) {
            acc.x += w[k] * x[v][k].x;
            acc.y += w[k] * x[v][k].y;
            acc.z += w[k] * x[v][k].z;
            acc.w += w[k] * x[v][k].w;
        }
        orow[tid + v * 256] = acc;
    }
}

// Generic fallback (any hidden/top_k).
__global__ __launch_bounds__(256) void moe_gather_generic(
    const float* __restrict__ moe, const float* __restrict__ scores,
    const int* __restrict__ slots, float* __restrict__ out,
    int hidden, int top_k) {
    const int t   = blockIdx.x;
    const int tid = threadIdx.x;
    const int nvec = hidden >> 2;
    const int K = top_k > 8 ? 8 : top_k;
    float w[8];
    const float4* rows[8];
    for (int k = 0; k < K; ++k) {
        const int s = slots[(size_t)t * top_k + k];
        w[k]    = scores[(size_t)t * top_k + k];
        rows[k] = (const float4*)(moe + (size_t)s * hidden);
    }
    float4* orow = (float4*)(out + (size_t)t * hidden);
    for (int v = tid; v < nvec; v += blockDim.x) {
        float4 acc = make_float4(0.f, 0.f, 0.f, 0.f);
        for (int k = 0; k < K; ++k) {
            float4 xx = rows[k][v];
            acc.x += w[k] * xx.x;
            acc.y += w[k] * xx.y;
            acc.z += w[k] * xx.z;
            acc.w += w[k] * xx.w;
        }
        orow[v] = acc;
    }
}

extern "C" void kernel_launch(void* const* d_in, const int* in_sizes, int n_in,
                              void* d_out, int out_size, void* d_ws, size_t ws_size,
                              hipStream_t stream) {
    const float* moe    = (const float*)d_in[0];
    const float* scores = (const float*)d_in[1];
    const int*   slots  = (const int*)d_in[2];
    float* out = (float*)d_out;

    const int total_slots = in_sizes[1];                // 16384
    const int hidden      = in_sizes[0] / total_slots;  // 2048
    const int n_tokens    = out_size / hidden;          // 8192
    const int top_k       = total_slots / n_tokens;     // 2

    if (top_k == 2 && hidden == 2048) {
        // 2048 floats = 512 float4 per row; 256 threads -> VPT=2.
        moe_gather_fixed<2, 2><<<n_tokens, 256, 0, stream>>>(
            moe, scores, slots, out, hidden);
    } else {
        moe_gather_generic<<<n_tokens, 256, 0, stream>>>(
            moe, scores, slots, out, hidden, top_k);
    }
}